// Round 9
// baseline (209.738 us; speedup 1.0000x reference)
//
#include <hip/hip_runtime.h>
#include <stdint.h>

#define N 8192
#define NCLS 80
#define NWD 128             // keep-mask words (8192 bits)
#define PAIR_CAP (1 << 16)  // 64K edges (256 KB); expected E ~ 2K
#define NT 128              // 64-box tiles per dimension (full 8192 capacity)
#define NTASK (NT * (NT + 1) / 2)   // 8256 upper-tri wave-tasks
#define K2_BLOCKS (NTASK / 4)       // 2064 blocks of 4 waves

__device__ __forceinline__ float rlane(float v, int k) {
    return __int_as_float(__builtin_amdgcn_readlane(__float_as_int(v), k));
}

// ---------------- K1: argmax + optimistic outputs + compaction ----------
// 8 threads/box. Outputs written as if keep==valid (k_main's tail corrects
// the few suppressed boxes). Valid boxes compacted via atomicAdd (arbitrary
// order is fine: suppression direction comes from (conf, orig idx)).
__global__ void __launch_bounds__(256) k_prep(
    const float* __restrict__ box, const float* __restrict__ conf,
    const float* __restrict__ logits,
    float4* __restrict__ sbx, float4* __restrict__ smeta,
    int* __restrict__ cnt, float* __restrict__ out)
{
#pragma clang fp contract(off)
    int gid = blockIdx.x * 256 + threadIdx.x;      // 0..65535
    int i = gid >> 3, s = gid & 7;
    const float4* lp = (const float4*)(logits + (size_t)i * NCLS);
    float best = -INFINITY; int bi = 0;
#pragma unroll
    for (int k2 = 0; k2 < 3; ++k2) {
        int c4 = s + 8 * k2;                       // 20 float4 chunks / 8 lanes
        if (c4 < 20) {
            float4 v = lp[c4]; int b = c4 * 4;
            if (v.x > best) { best = v.x; bi = b; }
            if (v.y > best) { best = v.y; bi = b + 1; }
            if (v.z > best) { best = v.z; bi = b + 2; }
            if (v.w > best) { best = v.w; bi = b + 3; }
        }
    }
    // 8-lane butterfly; ties -> lowest index (jnp first-max)
#pragma unroll
    for (int off = 1; off < 8; off <<= 1) {
        float ob = __shfl_xor(best, off, 8);
        int   oi = __shfl_xor(bi, off, 8);
        if (ob > best || (ob == best && oi < bi)) { best = ob; bi = oi; }
    }
    if (s == 0) {
        float c = conf[i];
        float m = (c > 0.5f) ? 1.0f : 0.0f;
        float4 b = ((const float4*)box)[i];        // x, y, w, h
        out[i * 5 + 0] = b.x * m;                  // x*1.0f == x bitwise
        out[i * 5 + 1] = b.y * m;
        out[i * 5 + 2] = b.z * m;
        out[i * 5 + 3] = b.w * m;
        out[i * 5 + 4] = c * m;
        out[5 * N + i] = (float)bi;
        out[6 * N + i] = m;
        if (c > 0.5f) {
            int cid = atomicAdd(&cnt[0], 1);
            float hw = b.z * 0.5f, hh = b.w * 0.5f;  // == w/2 exactly
            sbx[cid]   = make_float4(b.x - hw, b.y - hh, b.x + hw, b.y + hh);
            smeta[cid] = make_float4(b.z * b.w, c, (float)bi, (float)i);
        }
    }
}

// ---------------- K2: register-resident pair scan + last-block tail -----
// Each wave owns one 64x64 tile of the compact upper triangle. Rows AND
// cols live in lane registers; the 64-iter loop broadcasts col k via
// readlane -- NO memory access in the hot loop (the R4-R8 kernels were all
// LDS-latency-bound at ~600 cyc/iter; this is ~40). Rare candidates
// (~0.3% of pairs) take the exact __fdiv_rn IoU + directed-edge emit.
// Last finishing block: Jacobi fixpoint + sparse output correction.
__global__ void __launch_bounds__(256) k_main(
    const float4* __restrict__ sbx, const float4* __restrict__ smeta,
    int* __restrict__ cnt,              // [0]=V [1]=paircnt [2]=done
    unsigned int* __restrict__ pairs, float* __restrict__ out)
{
#pragma clang fp contract(off)
    int tid = threadIdx.x, wv = tid >> 6, lane = tid & 63;
    int V = cnt[0];

    // decode wave-task T -> (ti, tj), ti <= tj < 128 (column-major tri)
    int T = blockIdx.x * 4 + wv;
    int tj = (int)((sqrt(8.0 * (double)T + 1.0) - 1.0) * 0.5);
    int tri = (tj * (tj + 1)) >> 1;
    while (tri > T) { --tj; tri -= tj + 1; }
    while (T - tri > tj) { tri += tj + 1; ++tj; }
    int ti = T - tri;

    if ((tj << 6) < V) {                 // tile has any valid pair (ti<=tj)
        int rb = ti << 6, cb = tj << 6;
        int r = rb + lane;
        float4 rg = sbx[r];              // row geometry (x1,y1,x2,y2)
        float4 rm = smeta[r];            // (area, conf, cls, idx)
        float4 cg = sbx[cb + lane];      // this lane's COLUMN data
        float4 cm = smeta[cb + lane];
        bool rv = (r < V);
        bool diag = (ti == tj);
        for (int k = 0; k < 64; ++k) {
            // broadcast col k from lane k: pure VALU, no memory
            float cx1 = rlane(cg.x, k), cy1 = rlane(cg.y, k);
            float cx2 = rlane(cg.z, k), cy2 = rlane(cg.w, k);
            float ccl = rlane(cm.z, k);
            float iw = fminf(rg.z, cx2) - fmaxf(rg.x, cx1);
            float ih = fminf(rg.w, cy2) - fmaxf(rg.y, cy1);
            bool cv = (cb + k) < V;      // uniform
            bool pc = rv & cv & (ccl == rm.z) & (iw > 0.0f) & (ih > 0.0f)
                    & (!diag | (k > lane));
            if (__any(pc)) {             // rare; operands all in registers
                float carea = rlane(cm.x, k);
                float cconf = rlane(cm.y, k);
                // exact float32 op order of the reference:
                float iwc = fmaxf(iw, 0.0f);
                float ihc = fmaxf(ih, 0.0f);
                float inter = iwc * ihc;
                float uni = rm.x + carea - inter;    // area_r + area_c - inter
                float iou = __fdiv_rn(inter, uni);   // IEEE divide
                if (pc && iou > 0.5f) {
                    float cidx = rlane(cm.w, k);
                    int c = cb + k;
                    // earlier in (conf desc, orig idx asc) suppresses later
                    bool rEarlier = (rm.y > cconf) | ((rm.y == cconf) & (rm.w < cidx));
                    unsigned int e = rEarlier
                        ? (((unsigned)r << 13) | (unsigned)c)
                        : (((unsigned)c << 13) | (unsigned)r);
                    int idx = atomicAdd(&cnt[1], 1);
                    if (idx < PAIR_CAP) pairs[idx] = e;
                }
            }
        }
    }

    // ---- completion protocol: last block does the serial tail ----
    __shared__ int lastflag;
    __threadfence();                     // release pair writes
    __syncthreads();
    if (tid == 0) lastflag = (atomicAdd(&cnt[2], 1) == K2_BLOCKS - 1);
    __syncthreads();
    if (!lastflag) return;
    __threadfence();                     // acquire all blocks' pairs

    // ---- Jacobi fixpoint over sparse suppression DAG (LDS) ----
    // keep_{t+1}[v] = valid[v] & !exists edge u->v with keep_t[u]; edges
    // follow key order (DAG) => unique fixpoint == sequential greedy scan.
    __shared__ unsigned long long keep[NWD], sn[NWD], vmw[NWD];
    __shared__ int chg;
    int E = cnt[1]; if (E > PAIR_CAP) E = PAIR_CAP;
    int fullw = V >> 6, remv = V & 63;
    if (tid < NWD) {
        unsigned long long vm = (tid < fullw) ? ~0ULL
            : (tid == fullw && remv) ? ((1ULL << remv) - 1ULL) : 0ULL;
        vmw[tid] = vm;
        keep[tid] = vm;                  // K0 = all compacted (valid)
    }
    __syncthreads();
    for (int round = 0; round < 8192; ++round) {
        if (tid < NWD) sn[tid] = 0ULL;
        if (tid == 0) chg = 0;
        __syncthreads();
        for (int e = tid; e < E; e += 256) {
            unsigned int p = pairs[e];
            int u = p >> 13, v = p & 8191;
            if ((keep[u >> 6] >> (u & 63)) & 1ULL)
                atomicOr(&sn[v >> 6], 1ULL << (v & 63));
        }
        __syncthreads();
        if (tid < NWD) {
            unsigned long long nk = vmw[tid] & ~sn[tid];
            if (nk != keep[tid]) { keep[tid] = nk; chg = 1; }
        }
        __syncthreads();
        if (!chg) break;
    }

    // ---- sparse output correction: zero the suppressed boxes ----
    if (tid < NWD) {
        unsigned long long sup = vmw[tid] & ~keep[tid];   // keep subset valid
        while (sup) {
            int b = __builtin_ctzll(sup);
            sup &= sup - 1;
            int cid = (tid << 6) + b;
            int orig = (int)smeta[cid].w;                 // exact for idx<8192
            out[orig * 5 + 0] = 0.0f;
            out[orig * 5 + 1] = 0.0f;
            out[orig * 5 + 2] = 0.0f;
            out[orig * 5 + 3] = 0.0f;
            out[orig * 5 + 4] = 0.0f;
            out[6 * N + orig] = 0.0f;                     // cls stays unmasked
        }
    }
}

// ---------------- launch -------------------------------------------------
extern "C" void kernel_launch(void* const* d_in, const int* in_sizes, int n_in,
                              void* d_out, int out_size, void* d_ws, size_t ws_size,
                              hipStream_t stream) {
    const float* box    = (const float*)d_in[0];
    const float* conf   = (const float*)d_in[1];
    const float* logits = (const float*)d_in[2];
    float* out = (float*)d_out;

    char* ws = (char*)d_ws;
    int* cnt      = (int*)(ws + 0);                       // V / paircnt / done
    float4* sbx   = (float4*)(ws + 4096);                 // 128 KB corners
    float4* smeta = (float4*)(ws + 135168);               // 128 KB area/conf/cls/idx
    unsigned int* pairs = (unsigned int*)(ws + 266240);   // 256 KB

    hipMemsetAsync(cnt, 0, 12, stream);
    k_prep<<<256, 256, 0, stream>>>(box, conf, logits, sbx, smeta, cnt, out);
    k_main<<<K2_BLOCKS, 256, 0, stream>>>(sbx, smeta, cnt, pairs, out);
}